// Round 11
// baseline (151.700 us; speedup 1.0000x reference)
//
#include <hip/hip_runtime.h>

#define TPB 256

// r25: single-variable occupancy probe. r24 (hull-formula sweep, exact,
// absmax 0.0) was time-neutral vs r22 despite ~1300 fewer ops. Untested
// variable: r24's VGPR count under launch_bounds(256,2) (cap 256). If the
// allocator drifted past 128, only 3 waves/SIMD fit (grid supplies 4) ->
// -25% issue capacity, masking the op cut. This round pins (256,4)
// (VGPR<=128). Everything else byte-identical to r24.
// Readout: VGPR/WRITE_SIZE if main surfaces; else total: ~95 = occupancy
// was the mask; >=110 = pin-induced spill; ~100 = r24 already 4-wave,
// floor is structural.
__global__ __launch_bounds__(TPB, 4) void ciou_main(
    const float* __restrict__ A,
    const float* __restrict__ Bq,
    double* __restrict__ partial,
    int nbatch, int tail)
{
    const int t = threadIdx.x;
    const int i0 = blockIdx.x * TPB + t;
    const bool live = !tail || (i0 < nbatch);
    const int i = live ? i0 : (nbatch - 1);

    float ax0,ax1,ax2,ax3,ax4,ax5,ax6,ax7;
    float ay0,ay1,ay2,ay3,ay4,ay5,ay6,ay7;
    float bx0,bx1,bx2,bx3,bx4,bx5,bx6,bx7;
    float by0,by1,by2,by3,by4,by5,by6,by7;
    {
        const float4* pa = (const float4*)(A + (size_t)i * 16);
        const float4* pb = (const float4*)(Bq + (size_t)i * 16);
        float4 q;
        q = pa[0]; ax0=q.x; ay0=q.y; ax1=q.z; ay1=q.w;
        q = pa[1]; ax2=q.x; ay2=q.y; ax3=q.z; ay3=q.w;
        q = pa[2]; ax4=q.x; ay4=q.y; ax5=q.z; ay5=q.w;
        q = pa[3]; ax6=q.x; ay6=q.y; ax7=q.z; ay7=q.w;
        q = pb[0]; bx0=q.x; by0=q.y; bx1=q.z; by1=q.w;
        q = pb[1]; bx2=q.x; by2=q.y; bx3=q.z; by3=q.w;
        q = pb[2]; bx4=q.x; by4=q.y; bx5=q.z; by5=q.w;
        q = pb[3]; bx6=q.x; by6=q.y; bx7=q.z; by7=q.w;
    }

    // Edge vectors and shoelace crosses (hoisted once, reused everywhere).
#define MKEA(I,IN) float eax##I = ax##IN - ax##I, eay##I = ay##IN - ay##I;
#define MKEB(I,IN) float ebx##I = bx##IN - bx##I, eby##I = by##IN - by##I;
    MKEA(0,1) MKEA(1,2) MKEA(2,3) MKEA(3,4)
    MKEA(4,5) MKEA(5,6) MKEA(6,7) MKEA(7,0)
    MKEB(0,1) MKEB(1,2) MKEB(2,3) MKEB(3,4)
    MKEB(4,5) MKEB(5,6) MKEB(6,7) MKEB(7,0)
#define MKCA(I,IN) float ca##I = ax##I*ay##IN - ay##I*ax##IN;
#define MKCB(I,IN) float cb##I = bx##I*by##IN - by##I*bx##IN;
    MKCA(0,1) MKCA(1,2) MKCA(2,3) MKCA(3,4)
    MKCA(4,5) MKCA(5,6) MKCA(6,7) MKCA(7,0)
    MKCB(0,1) MKCB(1,2) MKCB(2,3) MKCB(3,4)
    MKCB(4,5) MKCB(5,6) MKCB(6,7) MKCB(7,0)
    float area_a = 0.5f * (((ca0+ca1)+(ca2+ca3)) + ((ca4+ca5)+(ca6+ca7)));
    float area_b = 0.5f * (((cb0+cb1)+(cb2+cb3)) + ((cb4+cb5)+(cb6+cb7)));

    // ---- Intersection: Green's theorem over clipped edges (r22 verbatim) --
    float inter2 = 0.f;

#define HP(T0,T1,EX,EY,CC) { \
        float aa = EX*Py - EY*Px + (CC); \
        float bb = EX*Dy - EY*Dx; \
        float tc = __fdividef(-aa, bb); \
        float h = bb * 1e38f; \
        T0 = fmaxf(T0, fminf(tc, h)); \
        T1 = fminf(T1, fmaxf(tc, h)); }

#define HPB HP(t0a,t1a, ebx0,eby0,cb0) HP(t0b,t1b, ebx1,eby1,cb1) \
            HP(t0a,t1a, ebx2,eby2,cb2) HP(t0b,t1b, ebx3,eby3,cb3) \
            HP(t0a,t1a, ebx4,eby4,cb4) HP(t0b,t1b, ebx5,eby5,cb5) \
            HP(t0a,t1a, ebx6,eby6,cb6) HP(t0b,t1b, ebx7,eby7,cb7)
#define HPA HP(t0a,t1a, eax0,eay0,ca0) HP(t0b,t1b, eax1,eay1,ca1) \
            HP(t0a,t1a, eax2,eay2,ca2) HP(t0b,t1b, eax3,eay3,ca3) \
            HP(t0a,t1a, eax4,eay4,ca4) HP(t0b,t1b, eax5,eay5,ca5) \
            HP(t0a,t1a, eax6,eay6,ca6) HP(t0b,t1b, eax7,eay7,ca7)

#define EDGE(PX,PY,DX,DY,CPD,HPS) { \
        const float Px = (PX), Py = (PY); \
        const float Dx = (DX), Dy = (DY); \
        float t0a = 0.f, t1a = 1.f, t0b = 0.f, t1b = 1.f; \
        HPS \
        float dt = fminf(t1a, t1b) - fmaxf(t0a, t0b); \
        inter2 += fmaxf(dt, 0.f) * (CPD); }

    EDGE(ax0,ay0, eax0,eay0, ca0, HPB) EDGE(ax1,ay1, eax1,eay1, ca1, HPB)
    EDGE(ax2,ay2, eax2,eay2, ca2, HPB) EDGE(ax3,ay3, eax3,eay3, ca3, HPB)
    EDGE(ax4,ay4, eax4,eay4, ca4, HPB) EDGE(ax5,ay5, eax5,eay5, ca5, HPB)
    EDGE(ax6,ay6, eax6,eay6, ca6, HPB) EDGE(ax7,ay7, eax7,eay7, ca7, HPB)
    EDGE(bx0,by0, ebx0,eby0, cb0, HPA) EDGE(bx1,by1, ebx1,eby1, cb1, HPA)
    EDGE(bx2,by2, ebx2,eby2, cb2, HPA) EDGE(bx3,by3, ebx3,eby3, cb3, HPA)
    EDGE(bx4,by4, ebx4,eby4, cb4, HPA) EDGE(bx5,by5, ebx5,eby5, cb5, HPA)
    EDGE(bx6,by6, ebx6,eby6, cb6, HPA) EDGE(bx7,by7, ebx7,eby7, cb7, HPA)

    float inter = fmaxf(0.5f * inter2, 0.f);
    float uni = area_a + area_b - inter;
    float iou = __fdividef(inter, uni);

    // ---- Hull area: bridge-pair sweep with byproduct masks (r24) ----
    float hbp = 0.f, hbm = 0.f, eSa = 0.f;
    float mbmin0=1e38f, mbmin1=1e38f, mbmin2=1e38f, mbmin3=1e38f,
          mbmin4=1e38f, mbmin5=1e38f, mbmin6=1e38f, mbmin7=1e38f;

#define BR2(EBXJ,EBYJ, EBXP,EBYP, BXJ,BYJ, MB) { \
        float Dx = (BXJ) - rax, Dy = (BYJ) - ray; \
        float c1 = Dx*reay - Dy*reax; \
        float c2 = Dx*peay - Dy*peax; \
        float c3 = Dx*(EBYJ) - Dy*(EBXJ); \
        float c4 = Dx*(EBYP) - Dy*(EBXP); \
        float cx = rax*(BYJ) - ray*(BXJ); \
        MB = fminf(MB, c3); \
        rmax = fmaxf(rmax, c1); \
        float mn = fminf(fminf(c1, -c2), fminf(c3, -c4)); \
        float mx = fmaxf(fmaxf(c1, -c2), fmaxf(c3, -c4)); \
        hbp += (mn >= 0.f) ? cx : 0.f; \
        hbm += (mx <= 0.f) ? cx : 0.f; }

#define BRROW(AXI,AYI, EAXI,EAYI, EAXP,EAYP, CAI) { \
        float rax = (AXI), ray = (AYI); \
        asm volatile("" : "+v"(rax), "+v"(ray) : "v"(hbp), "v"(hbm)); \
        const float reax = (EAXI), reay = (EAYI); \
        const float peax = (EAXP), peay = (EAYP); \
        float rmax = -1e38f; \
        BR2(ebx0,eby0, ebx7,eby7, bx0,by0, mbmin0) \
        BR2(ebx1,eby1, ebx0,eby0, bx1,by1, mbmin1) \
        BR2(ebx2,eby2, ebx1,eby1, bx2,by2, mbmin2) \
        BR2(ebx3,eby3, ebx2,eby2, bx3,by3, mbmin3) \
        BR2(ebx4,eby4, ebx3,eby3, bx4,by4, mbmin4) \
        BR2(ebx5,eby5, ebx4,eby4, bx5,by5, mbmin5) \
        BR2(ebx6,eby6, ebx5,eby5, bx6,by6, mbmin6) \
        BR2(ebx7,eby7, ebx6,eby6, bx7,by7, mbmin7) \
        eSa += (rmax <= 0.f) ? (CAI) : 0.f; }

    BRROW(ax0,ay0, eax0,eay0, eax7,eay7, ca0)
    BRROW(ax1,ay1, eax1,eay1, eax0,eay0, ca1)
    BRROW(ax2,ay2, eax2,eay2, eax1,eay1, ca2)
    BRROW(ax3,ay3, eax3,eay3, eax2,eay2, ca3)
    BRROW(ax4,ay4, eax4,eay4, eax3,eay3, ca4)
    BRROW(ax5,ay5, eax5,eay5, eax4,eay4, ca5)
    BRROW(ax6,ay6, eax6,eay6, eax5,eay5, ca6)
    BRROW(ax7,ay7, eax7,eay7, eax6,eay6, ca7)

    float eSb = (((mbmin0 >= 0.f ? cb0 : 0.f) + (mbmin1 >= 0.f ? cb1 : 0.f))
              +  ((mbmin2 >= 0.f ? cb2 : 0.f) + (mbmin3 >= 0.f ? cb3 : 0.f)))
              + (((mbmin4 >= 0.f ? cb4 : 0.f) + (mbmin5 >= 0.f ? cb5 : 0.f))
              +  ((mbmin6 >= 0.f ? cb6 : 0.f) + (mbmin7 >= 0.f ? cb7 : 0.f)));
    float ch = 0.5f * ((eSa + eSb) + (hbp - hbm));

    float val = iou - __fdividef(ch - uni, ch);
    float v = live ? val : 0.f;

    // ---- epilogue: shuffle -> LDS(16B) -> ONE plain store. Zero waits. ----
    #pragma unroll
    for (int off = 32; off > 0; off >>= 1) v += __shfl_down(v, off);
    __shared__ float wsum[4];
    int lane = t & 63, wid = t >> 6;
    if (lane == 0) wsum[wid] = v;
    __syncthreads();
    if (t == 0) {
        partial[blockIdx.x] = (double)wsum[0] + (double)wsum[1]
                            + (double)wsum[2] + (double)wsum[3];
    }
}

__global__ __launch_bounds__(256) void ciou_finalize(
    const double* __restrict__ partial, float* __restrict__ out,
    int nparts, int nbatch)
{
    double v = 0.0;
    for (int j = threadIdx.x; j < nparts; j += 256) v += partial[j];
    #pragma unroll
    for (int off = 32; off > 0; off >>= 1) v += __shfl_down(v, off);
    __shared__ double s[4];
    int lane = threadIdx.x & 63, wid = threadIdx.x >> 6;
    if (lane == 0) s[wid] = v;
    __syncthreads();
    if (threadIdx.x == 0)
        out[0] = (float)((s[0] + s[1] + s[2] + s[3]) / (double)nbatch);
}

extern "C" void kernel_launch(void* const* d_in, const int* in_sizes, int n_in,
                              void* d_out, int out_size, void* d_ws, size_t ws_size,
                              hipStream_t stream) {
    const float* a = (const float*)d_in[0];
    const float* b = (const float*)d_in[1];
    float* out = (float*)d_out;
    int nbatch = in_sizes[0] / 16;
    int nblocks = (nbatch + TPB - 1) / TPB;   // 262144 -> 1024, exact
    int tail = (nblocks * TPB != nbatch) ? 1 : 0;
    double* partial = (double*)d_ws;   // fully overwritten each call; no memset
    ciou_main<<<nblocks, TPB, 0, stream>>>(a, b, partial, nbatch, tail);
    ciou_finalize<<<1, 256, 0, stream>>>(partial, out, nblocks, nbatch);
}

// Round 12
// 104.408 us; speedup vs baseline: 1.4529x; 1.4529x over previous
//
#include <hip/hip_runtime.h>

#define TPB 256
#define EPB 128   // elements per block (2 waves clip + 2 waves sweep)

// r26: wave-specialization occupancy round. Clean-run ledger r16..r24: main
// pinned 39-41us across 2900-4500-op variants (sub-linear to op cuts,
// VALUBusy ~73%) -> mixed issue/latency, and waves/SIMD grid-capped at 4
// (1 thread/element). This round: 2 waves per 64 elements. Block of 256:
// waves 0-1 = clip (r22 verbatim -> iou,uni), waves 2-3 = r24 bridge sweep
// (-> ch) for the SAME 128 elements; chbuf[128] LDS handoff at the existing
// barrier. Wave-uniform roles (no lane divergence). Supplied occupancy
// 4 -> 8 waves/SIMD; VGPR dieted to ~80 (D-inline EDGE, per-row ea
// recompute, cb deferred to eSb) -> ~6 resident. Element math bit-identical
// to r22/r24 (both absmax 0.0). r25's (256,4) pin was toxic (64-VGPR spill,
// 187MB scratch) -> back to (256,2).
__global__ __launch_bounds__(TPB, 2) void ciou_main(
    const float* __restrict__ A,
    const float* __restrict__ Bq,
    double* __restrict__ partial,
    int nbatch, int tail)
{
    const int t = threadIdx.x;
    const int el = t & 127;               // element slot within block
    const bool clipRole = t < 128;        // waves 0-1 clip, waves 2-3 sweep
    const int e0 = blockIdx.x * EPB + el;
    const bool live = !tail || (e0 < nbatch);
    const int i = live ? e0 : (nbatch - 1);

    float ax0,ax1,ax2,ax3,ax4,ax5,ax6,ax7;
    float ay0,ay1,ay2,ay3,ay4,ay5,ay6,ay7;
    float bx0,bx1,bx2,bx3,bx4,bx5,bx6,bx7;
    float by0,by1,by2,by3,by4,by5,by6,by7;
    {
        const float4* pa = (const float4*)(A + (size_t)i * 16);
        const float4* pb = (const float4*)(Bq + (size_t)i * 16);
        float4 q;
        q = pa[0]; ax0=q.x; ay0=q.y; ax1=q.z; ay1=q.w;
        q = pa[1]; ax2=q.x; ay2=q.y; ax3=q.z; ay3=q.w;
        q = pa[2]; ax4=q.x; ay4=q.y; ax5=q.z; ay5=q.w;
        q = pa[3]; ax6=q.x; ay6=q.y; ax7=q.z; ay7=q.w;
        q = pb[0]; bx0=q.x; by0=q.y; bx1=q.z; by1=q.w;
        q = pb[1]; bx2=q.x; by2=q.y; bx3=q.z; by3=q.w;
        q = pb[2]; bx4=q.x; by4=q.y; bx5=q.z; by5=q.w;
        q = pb[3]; bx6=q.x; by6=q.y; bx7=q.z; by7=q.w;
    }

    __shared__ float chbuf[EPB];
    __shared__ float wsum[4];

    float iou = 0.f, uni = 1.f;

#define MKCA(I,IN) float ca##I = ax##I*ay##IN - ay##I*ax##IN;
#define MKCB(I,IN) float cb##I = bx##I*by##IN - by##I*bx##IN;
#define MKEA(I,IN) float eax##I = ax##IN - ax##I, eay##I = ay##IN - ay##I;
#define MKEB(I,IN) float ebx##I = bx##IN - bx##I, eby##I = by##IN - by##I;

#define HP(T0,T1,EX,EY,CC) { \
        float aa = EX*Py - EY*Px + (CC); \
        float bb = EX*Dy - EY*Dx; \
        float tc = __fdividef(-aa, bb); \
        float h = bb * 1e38f; \
        T0 = fmaxf(T0, fminf(tc, h)); \
        T1 = fminf(T1, fmaxf(tc, h)); }

#define HPB HP(t0a,t1a, ebx0,eby0,cb0) HP(t0b,t1b, ebx1,eby1,cb1) \
            HP(t0a,t1a, ebx2,eby2,cb2) HP(t0b,t1b, ebx3,eby3,cb3) \
            HP(t0a,t1a, ebx4,eby4,cb4) HP(t0b,t1b, ebx5,eby5,cb5) \
            HP(t0a,t1a, ebx6,eby6,cb6) HP(t0b,t1b, ebx7,eby7,cb7)
#define HPA HP(t0a,t1a, eax0,eay0,ca0) HP(t0b,t1b, eax1,eay1,ca1) \
            HP(t0a,t1a, eax2,eay2,ca2) HP(t0b,t1b, eax3,eay3,ca3) \
            HP(t0a,t1a, eax4,eay4,ca4) HP(t0b,t1b, eax5,eay5,ca5) \
            HP(t0a,t1a, eax6,eay6,ca6) HP(t0b,t1b, eax7,eay7,ca7)

    // EDGE with D inlined from endpoint coords (bit-identical to evec form).
#define EDGE(PX,PY,QX,QY,CPD,HPS) { \
        const float Px = (PX), Py = (PY); \
        const float Dx = (QX) - Px, Dy = (QY) - Py; \
        float t0a = 0.f, t1a = 1.f, t0b = 0.f, t1b = 1.f; \
        HPS \
        float dt = fminf(t1a, t1b) - fmaxf(t0a, t0b); \
        inter2 += fmaxf(dt, 0.f) * (CPD); }

    if (clipRole) {
        // ================= CLIP role (r22 math, verbatim order) ===========
        MKCA(0,1) MKCA(1,2) MKCA(2,3) MKCA(3,4)
        MKCA(4,5) MKCA(5,6) MKCA(6,7) MKCA(7,0)
        MKCB(0,1) MKCB(1,2) MKCB(2,3) MKCB(3,4)
        MKCB(4,5) MKCB(5,6) MKCB(6,7) MKCB(7,0)
        float area_a = 0.5f * (((ca0+ca1)+(ca2+ca3)) + ((ca4+ca5)+(ca6+ca7)));
        float area_b = 0.5f * (((cb0+cb1)+(cb2+cb3)) + ((cb4+cb5)+(cb6+cb7)));
        float inter2 = 0.f;
        {   // pass 1: A-edges vs B half-planes (eb scoped here)
            MKEB(0,1) MKEB(1,2) MKEB(2,3) MKEB(3,4)
            MKEB(4,5) MKEB(5,6) MKEB(6,7) MKEB(7,0)
            EDGE(ax0,ay0, ax1,ay1, ca0, HPB) EDGE(ax1,ay1, ax2,ay2, ca1, HPB)
            EDGE(ax2,ay2, ax3,ay3, ca2, HPB) EDGE(ax3,ay3, ax4,ay4, ca3, HPB)
            EDGE(ax4,ay4, ax5,ay5, ca4, HPB) EDGE(ax5,ay5, ax6,ay6, ca5, HPB)
            EDGE(ax6,ay6, ax7,ay7, ca6, HPB) EDGE(ax7,ay7, ax0,ay0, ca7, HPB)
        }
        {   // pass 2: B-edges vs A half-planes (ea scoped here)
            MKEA(0,1) MKEA(1,2) MKEA(2,3) MKEA(3,4)
            MKEA(4,5) MKEA(5,6) MKEA(6,7) MKEA(7,0)
            EDGE(bx0,by0, bx1,by1, cb0, HPA) EDGE(bx1,by1, bx2,by2, cb1, HPA)
            EDGE(bx2,by2, bx3,by3, cb2, HPA) EDGE(bx3,by3, bx4,by4, cb3, HPA)
            EDGE(bx4,by4, bx5,by5, cb4, HPA) EDGE(bx5,by5, bx6,by6, cb5, HPA)
            EDGE(bx6,by6, bx7,by7, cb6, HPA) EDGE(bx7,by7, bx0,by0, cb7, HPA)
        }
        float inter = fmaxf(0.5f * inter2, 0.f);
        uni = area_a + area_b - inter;
        iou = __fdividef(inter, uni);
    } else {
        // ================= SWEEP role (r24 math) ==========================
        MKEB(0,1) MKEB(1,2) MKEB(2,3) MKEB(3,4)
        MKEB(4,5) MKEB(5,6) MKEB(6,7) MKEB(7,0)
        float hbp = 0.f, hbm = 0.f, eSa = 0.f;
        float mbmin0=1e38f, mbmin1=1e38f, mbmin2=1e38f, mbmin3=1e38f,
              mbmin4=1e38f, mbmin5=1e38f, mbmin6=1e38f, mbmin7=1e38f;

#define BR2(EBXJ,EBYJ, EBXP,EBYP, BXJ,BYJ, MB) { \
        float Dx = (BXJ) - rax, Dy = (BYJ) - ray; \
        float c1 = Dx*reay - Dy*reax; \
        float c2 = Dx*peay - Dy*peax; \
        float c3 = Dx*(EBYJ) - Dy*(EBXJ); \
        float c4 = Dx*(EBYP) - Dy*(EBXP); \
        float cx = rax*(BYJ) - ray*(BXJ); \
        MB = fminf(MB, c3); \
        rmax = fmaxf(rmax, c1); \
        float mn = fminf(fminf(c1, -c2), fminf(c3, -c4)); \
        float mx = fmaxf(fmaxf(c1, -c2), fmaxf(c3, -c4)); \
        hbp += (mn >= 0.f) ? cx : 0.f; \
        hbm += (mx <= 0.f) ? cx : 0.f; }

        // Row: A_i coords laundered (anti-hoist, r24); ea recomputed per
        // row (same expressions -> bit-identical); ca_i inline for eSa.
#define BRROW(AXI,AYI, AXN,AYN, AXP,AYP) { \
        float rax = (AXI), ray = (AYI); \
        asm volatile("" : "+v"(rax), "+v"(ray) : "v"(hbp), "v"(hbm)); \
        const float reax = (AXN) - (AXI), reay = (AYN) - (AYI); \
        const float peax = (AXI) - (AXP), peay = (AYI) - (AYP); \
        float rmax = -1e38f; \
        BR2(ebx0,eby0, ebx7,eby7, bx0,by0, mbmin0) \
        BR2(ebx1,eby1, ebx0,eby0, bx1,by1, mbmin1) \
        BR2(ebx2,eby2, ebx1,eby1, bx2,by2, mbmin2) \
        BR2(ebx3,eby3, ebx2,eby2, bx3,by3, mbmin3) \
        BR2(ebx4,eby4, ebx3,eby3, bx4,by4, mbmin4) \
        BR2(ebx5,eby5, ebx4,eby4, bx5,by5, mbmin5) \
        BR2(ebx6,eby6, ebx5,eby5, bx6,by6, mbmin6) \
        BR2(ebx7,eby7, ebx6,eby6, bx7,by7, mbmin7) \
        float cai = rax*(AYN) - ray*(AXN); \
        eSa += (rmax <= 0.f) ? cai : 0.f; }

        BRROW(ax0,ay0, ax1,ay1, ax7,ay7)
        BRROW(ax1,ay1, ax2,ay2, ax0,ay0)
        BRROW(ax2,ay2, ax3,ay3, ax1,ay1)
        BRROW(ax3,ay3, ax4,ay4, ax2,ay2)
        BRROW(ax4,ay4, ax5,ay5, ax3,ay3)
        BRROW(ax5,ay5, ax6,ay6, ax4,ay4)
        BRROW(ax6,ay6, ax7,ay7, ax5,ay5)
        BRROW(ax7,ay7, ax0,ay0, ax6,ay6)

        // eSb: cb_j computed here (deferred; same expressions as MKCB).
        MKCB(0,1) MKCB(1,2) MKCB(2,3) MKCB(3,4)
        MKCB(4,5) MKCB(5,6) MKCB(6,7) MKCB(7,0)
        float eSb = (((mbmin0 >= 0.f ? cb0 : 0.f) + (mbmin1 >= 0.f ? cb1 : 0.f))
                  +  ((mbmin2 >= 0.f ? cb2 : 0.f) + (mbmin3 >= 0.f ? cb3 : 0.f)))
                  + (((mbmin4 >= 0.f ? cb4 : 0.f) + (mbmin5 >= 0.f ? cb5 : 0.f))
                  +  ((mbmin6 >= 0.f ? cb6 : 0.f) + (mbmin7 >= 0.f ? cb7 : 0.f)));
        chbuf[el] = 0.5f * ((eSa + eSb) + (hbp - hbm));
    }

    __syncthreads();

    float v = 0.f;
    if (clipRole) {
        float ch = chbuf[el];
        float val = iou - __fdividef(ch - uni, ch);
        v = live ? val : 0.f;
    }

    // ---- epilogue: shuffle -> LDS(16B) -> ONE plain store ----
    #pragma unroll
    for (int off = 32; off > 0; off >>= 1) v += __shfl_down(v, off);
    int lane = t & 63, wid = t >> 6;
    if (lane == 0) wsum[wid] = v;
    __syncthreads();
    if (t == 0) {
        partial[blockIdx.x] = (double)wsum[0] + (double)wsum[1]
                            + (double)wsum[2] + (double)wsum[3];
    }
}

__global__ __launch_bounds__(256) void ciou_finalize(
    const double* __restrict__ partial, float* __restrict__ out,
    int nparts, int nbatch)
{
    double v = 0.0;
    for (int j = threadIdx.x; j < nparts; j += 256) v += partial[j];
    #pragma unroll
    for (int off = 32; off > 0; off >>= 1) v += __shfl_down(v, off);
    __shared__ double s[4];
    int lane = threadIdx.x & 63, wid = threadIdx.x >> 6;
    if (lane == 0) s[wid] = v;
    __syncthreads();
    if (threadIdx.x == 0)
        out[0] = (float)((s[0] + s[1] + s[2] + s[3]) / (double)nbatch);
}

extern "C" void kernel_launch(void* const* d_in, const int* in_sizes, int n_in,
                              void* d_out, int out_size, void* d_ws, size_t ws_size,
                              hipStream_t stream) {
    const float* a = (const float*)d_in[0];
    const float* b = (const float*)d_in[1];
    float* out = (float*)d_out;
    int nbatch = in_sizes[0] / 16;
    int nblocks = (nbatch + EPB - 1) / EPB;   // 262144 -> 2048, exact
    int tail = (nblocks * EPB != nbatch) ? 1 : 0;
    double* partial = (double*)d_ws;   // fully overwritten each call; no memset
    ciou_main<<<nblocks, TPB, 0, stream>>>(a, b, partial, nbatch, tail);
    ciou_finalize<<<1, 256, 0, stream>>>(partial, out, nblocks, nbatch);
}

// Round 13
// 90.412 us; speedup vs baseline: 1.6779x; 1.1548x over previous
//
#include <hip/hip_runtime.h>

#define TPB 256

// r27: unified 64-pair sweep — the last instruction-count lever.
// Identities (all verified in prior rounds): bb1(i,j)=cross(eb_j,ea_i)=ee,
// bb2(j,i)=-ee (rcp sign-symmetric -> ONE rcp per pair, 64 not 128);
// aa1=c3=cross(D,eb_j), aa2=-c1=-cross(D,ea_i) — same crosses the hull
// sweep needs. One pass computes D,ee,rr,c1..c4,cx per pair and feeds:
//   clip A-row interval (t0a/t1a), clip B-edge intervals (t0b/t1b_j,
//   persistent), hull masks (rmax_i, mbmin_j), bridges (hbp/hbm).
// Shoelace ca_i/cb_j fold into row/tail epilogues. ~2400 dyn-ops vs r22's
// ~4300. Spill control: r24's row asm-launder (proven), persistent set
// ~78 regs, peak ~100. Math formulas = r22/r23/r24 (each absmax 0.0);
// reassociation tolerance proven r21. Epilogue/finalize unchanged.
__global__ __launch_bounds__(TPB, 2) void ciou_main(
    const float* __restrict__ A,
    const float* __restrict__ Bq,
    double* __restrict__ partial,
    int nbatch, int tail)
{
    const int t = threadIdx.x;
    const int i0 = blockIdx.x * TPB + t;
    const bool live = !tail || (i0 < nbatch);
    const int i = live ? i0 : (nbatch - 1);

    float ax0,ax1,ax2,ax3,ax4,ax5,ax6,ax7;
    float ay0,ay1,ay2,ay3,ay4,ay5,ay6,ay7;
    float bx0,bx1,bx2,bx3,bx4,bx5,bx6,bx7;
    float by0,by1,by2,by3,by4,by5,by6,by7;
    {
        const float4* pa = (const float4*)(A + (size_t)i * 16);
        const float4* pb = (const float4*)(Bq + (size_t)i * 16);
        float4 q;
        q = pa[0]; ax0=q.x; ay0=q.y; ax1=q.z; ay1=q.w;
        q = pa[1]; ax2=q.x; ay2=q.y; ax3=q.z; ay3=q.w;
        q = pa[2]; ax4=q.x; ay4=q.y; ax5=q.z; ay5=q.w;
        q = pa[3]; ax6=q.x; ay6=q.y; ax7=q.z; ay7=q.w;
        q = pb[0]; bx0=q.x; by0=q.y; bx1=q.z; by1=q.w;
        q = pb[1]; bx2=q.x; by2=q.y; bx3=q.z; by3=q.w;
        q = pb[2]; bx4=q.x; by4=q.y; bx5=q.z; by5=q.w;
        q = pb[3]; bx6=q.x; by6=q.y; bx7=q.z; by7=q.w;
    }

    // B edge vectors (persistent, reused in all 64 pairs).
#define MKEB(I,IN) float ebx##I = bx##IN - bx##I, eby##I = by##IN - by##I;
    MKEB(0,1) MKEB(1,2) MKEB(2,3) MKEB(3,4)
    MKEB(4,5) MKEB(5,6) MKEB(6,7) MKEB(7,0)

    // Persistent sweep state.
    float t0b0=0.f,t0b1=0.f,t0b2=0.f,t0b3=0.f,t0b4=0.f,t0b5=0.f,t0b6=0.f,t0b7=0.f;
    float t1b0=1.f,t1b1=1.f,t1b2=1.f,t1b3=1.f,t1b4=1.f,t1b5=1.f,t1b6=1.f,t1b7=1.f;
    float mbmin0=1e38f,mbmin1=1e38f,mbmin2=1e38f,mbmin3=1e38f,
          mbmin4=1e38f,mbmin5=1e38f,mbmin6=1e38f,mbmin7=1e38f;
    float hbp = 0.f, hbm = 0.f, eSa = 0.f;
    float inter2 = 0.f, areaA2 = 0.f;

    // One pair (A-edge i row context x B vertex/edge j):
    //   ee = cross(eb_j, ea_i) = bb1; bb2 = -ee; rr = rcp(ee) (shared).
    //   c3 = cross(D, eb_j) = aa1;  c1 = cross(D, ea_i) = -aa2.
    //   tc1 = -c3*rr (h=ee*1e38); tc2 = -c1*rr (h2=-h).
    //   Bridges/masks: r24 semantics (c2/c4 = prev-edge crosses).
#define PAIR(J,JP) { \
        float Dx = bx##J - rax, Dy = by##J - ray; \
        float ee = ebx##J*reay - eby##J*reax; \
        float rr = __builtin_amdgcn_rcpf(ee); \
        float c1 = Dx*reay - Dy*reax; \
        float c3 = Dx*eby##J - Dy*ebx##J; \
        float c2 = Dx*peay - Dy*peax; \
        float c4 = Dx*eby##JP - Dy*ebx##JP; \
        float h = ee * 1e38f; \
        float tc1 = -c3 * rr; \
        t0a = fmaxf(t0a, fminf(tc1, h)); \
        t1a = fminf(t1a, fmaxf(tc1, h)); \
        float tc2 = -c1 * rr; \
        t0b##J = fmaxf(t0b##J, fminf(tc2, -h)); \
        t1b##J = fminf(t1b##J, fmaxf(tc2, -h)); \
        mbmin##J = fminf(mbmin##J, c3); \
        rmax = fmaxf(rmax, c1); \
        float mn = fminf(fminf(c1, -c2), fminf(c3, -c4)); \
        float mx = fmaxf(fmaxf(c1, -c2), fmaxf(c3, -c4)); \
        float cx = rax*by##J - ray*bx##J; \
        hbp += (mn >= 0.f) ? cx : 0.f; \
        hbm += (mx <= 0.f) ? cx : 0.f; }

    // Row for A-edge i: laundered A_i (anti-hoist, r24-proven), fresh
    // ea_i/ea_{i-1}, row-local clip interval + rmax; epilogue folds
    // shoelace ca_i into area, Green's sum, and eSa.
#define ROW(I,IN,IP) { \
        float rax = ax##I, ray = ay##I; \
        asm volatile("" : "+v"(rax), "+v"(ray) : "v"(hbp), "v"(hbm)); \
        const float reax = ax##IN - rax, reay = ay##IN - ray; \
        const float peax = rax - ax##IP, peay = ray - ay##IP; \
        float t0a = 0.f, t1a = 1.f, rmax = -1e38f; \
        PAIR(0,7) PAIR(1,0) PAIR(2,1) PAIR(3,2) \
        PAIR(4,3) PAIR(5,4) PAIR(6,5) PAIR(7,6) \
        float cai = rax*ay##IN - ray*ax##IN; \
        areaA2 += cai; \
        float dt = t1a - t0a; \
        inter2 += fmaxf(dt, 0.f) * cai; \
        eSa += (rmax <= 0.f) ? cai : 0.f; }

    ROW(0,1,7) ROW(1,2,0) ROW(2,3,1) ROW(3,4,2)
    ROW(4,5,3) ROW(5,6,4) ROW(6,7,5) ROW(7,0,6)

    // B-edge tails: shoelace cb_j + clipped Green's term + hull mask term.
    float areaB2 = 0.f, eSb = 0.f;
#define BTAIL(J,JN) { \
        float cbj = bx##J*by##JN - by##J*bx##JN; \
        areaB2 += cbj; \
        float dt = t1b##J - t0b##J; \
        inter2 += fmaxf(dt, 0.f) * cbj; \
        eSb += (mbmin##J >= 0.f) ? cbj : 0.f; }
    BTAIL(0,1) BTAIL(1,2) BTAIL(2,3) BTAIL(3,4)
    BTAIL(4,5) BTAIL(5,6) BTAIL(6,7) BTAIL(7,0)

    float inter = fmaxf(0.5f * inter2, 0.f);
    float uni = 0.5f * areaA2 + 0.5f * areaB2 - inter;
    float iou = __fdividef(inter, uni);
    float ch = 0.5f * ((eSa + eSb) + (hbp - hbm));

    float val = iou - __fdividef(ch - uni, ch);
    float v = live ? val : 0.f;

    // ---- epilogue: shuffle -> LDS(16B) -> ONE plain store. Zero waits. ----
    #pragma unroll
    for (int off = 32; off > 0; off >>= 1) v += __shfl_down(v, off);
    __shared__ float wsum[4];
    int lane = t & 63, wid = t >> 6;
    if (lane == 0) wsum[wid] = v;
    __syncthreads();
    if (t == 0) {
        partial[blockIdx.x] = (double)wsum[0] + (double)wsum[1]
                            + (double)wsum[2] + (double)wsum[3];
    }
}

__global__ __launch_bounds__(256) void ciou_finalize(
    const double* __restrict__ partial, float* __restrict__ out,
    int nparts, int nbatch)
{
    double v = 0.0;
    for (int j = threadIdx.x; j < nparts; j += 256) v += partial[j];
    #pragma unroll
    for (int off = 32; off > 0; off >>= 1) v += __shfl_down(v, off);
    __shared__ double s[4];
    int lane = threadIdx.x & 63, wid = threadIdx.x >> 6;
    if (lane == 0) s[wid] = v;
    __syncthreads();
    if (threadIdx.x == 0)
        out[0] = (float)((s[0] + s[1] + s[2] + s[3]) / (double)nbatch);
}

extern "C" void kernel_launch(void* const* d_in, const int* in_sizes, int n_in,
                              void* d_out, int out_size, void* d_ws, size_t ws_size,
                              hipStream_t stream) {
    const float* a = (const float*)d_in[0];
    const float* b = (const float*)d_in[1];
    float* out = (float*)d_out;
    int nbatch = in_sizes[0] / 16;
    int nblocks = (nbatch + TPB - 1) / TPB;   // 262144 -> 1024, exact
    int tail = (nblocks * TPB != nbatch) ? 1 : 0;
    double* partial = (double*)d_ws;   // fully overwritten each call; no memset
    ciou_main<<<nblocks, TPB, 0, stream>>>(a, b, partial, nbatch, tail);
    ciou_finalize<<<1, 256, 0, stream>>>(partial, out, nblocks, nbatch);
}

// Round 14
// 89.273 us; speedup vs baseline: 1.6993x; 1.0128x over previous
//
#include <hip/hip_runtime.h>

#define TPB 256

// r28: forwarding round on r27's unified sweep (90.4us total, the session
// win). Exact algebraic identities eliminate the last recomputation:
//   c2(i,j) = c1(i-1,j)   [cross(ea,ea)=0]  -> 8 persistent pc1_j,
//                                             row-0 seed = 8-pair prologue.
//   c4(i,j) = c3(i,j-1)   [cross(eb,eb)=0]  -> rolling pc3, j=0 seam direct.
//   mn/mx as left-chains -> v_min3/v_max3 fusion (3 ops -> 2).
// ~-270 static ops (-11%). Values algebraically identical; tolerance r21,
// sign-test robustness r23/r24. Everything else byte-identical to r27.
__global__ __launch_bounds__(TPB, 2) void ciou_main(
    const float* __restrict__ A,
    const float* __restrict__ Bq,
    double* __restrict__ partial,
    int nbatch, int tail)
{
    const int t = threadIdx.x;
    const int i0 = blockIdx.x * TPB + t;
    const bool live = !tail || (i0 < nbatch);
    const int i = live ? i0 : (nbatch - 1);

    float ax0,ax1,ax2,ax3,ax4,ax5,ax6,ax7;
    float ay0,ay1,ay2,ay3,ay4,ay5,ay6,ay7;
    float bx0,bx1,bx2,bx3,bx4,bx5,bx6,bx7;
    float by0,by1,by2,by3,by4,by5,by6,by7;
    {
        const float4* pa = (const float4*)(A + (size_t)i * 16);
        const float4* pb = (const float4*)(Bq + (size_t)i * 16);
        float4 q;
        q = pa[0]; ax0=q.x; ay0=q.y; ax1=q.z; ay1=q.w;
        q = pa[1]; ax2=q.x; ay2=q.y; ax3=q.z; ay3=q.w;
        q = pa[2]; ax4=q.x; ay4=q.y; ax5=q.z; ay5=q.w;
        q = pa[3]; ax6=q.x; ay6=q.y; ax7=q.z; ay7=q.w;
        q = pb[0]; bx0=q.x; by0=q.y; bx1=q.z; by1=q.w;
        q = pb[1]; bx2=q.x; by2=q.y; bx3=q.z; by3=q.w;
        q = pb[2]; bx4=q.x; by4=q.y; bx5=q.z; by5=q.w;
        q = pb[3]; bx6=q.x; by6=q.y; bx7=q.z; by7=q.w;
    }

    // B edge vectors (persistent, reused in all 64 pairs).
#define MKEB(I,IN) float ebx##I = bx##IN - bx##I, eby##I = by##IN - by##I;
    MKEB(0,1) MKEB(1,2) MKEB(2,3) MKEB(3,4)
    MKEB(4,5) MKEB(5,6) MKEB(6,7) MKEB(7,0)

    // Persistent sweep state.
    float t0b0=0.f,t0b1=0.f,t0b2=0.f,t0b3=0.f,t0b4=0.f,t0b5=0.f,t0b6=0.f,t0b7=0.f;
    float t1b0=1.f,t1b1=1.f,t1b2=1.f,t1b3=1.f,t1b4=1.f,t1b5=1.f,t1b6=1.f,t1b7=1.f;
    float mbmin0=1e38f,mbmin1=1e38f,mbmin2=1e38f,mbmin3=1e38f,
          mbmin4=1e38f,mbmin5=1e38f,mbmin6=1e38f,mbmin7=1e38f;
    float hbp = 0.f, hbm = 0.f, eSa = 0.f;
    float inter2 = 0.f, areaA2 = 0.f;

    // Row-0 c2 seed: pc1_j = c1(row 7, j) = cross(B_j - A_7, ea_7).
    float pc1_0,pc1_1,pc1_2,pc1_3,pc1_4,pc1_5,pc1_6,pc1_7;
    {
        const float e7x = ax0 - ax7, e7y = ay0 - ay7;   // ea_7
#define PC1(J) { float Dx = bx##J - ax7, Dy = by##J - ay7; \
                 pc1_##J = Dx*e7y - Dy*e7x; }
        PC1(0) PC1(1) PC1(2) PC1(3) PC1(4) PC1(5) PC1(6) PC1(7)
    }

    // One pair. c2 forwarded from pc1_j (prev row), c4 from pc3 (prev pair,
    // C4SRC); both exact algebraic identities. pc1_j/pc3 updated to this
    // pair's c1/c3 at the end.
#define PAIR(J, C4EXPR) { \
        float Dx = bx##J - rax, Dy = by##J - ray; \
        float ee = ebx##J*reay - eby##J*reax; \
        float rr = __builtin_amdgcn_rcpf(ee); \
        float c1 = Dx*reay - Dy*reax; \
        float c3 = Dx*eby##J - Dy*ebx##J; \
        float c2 = pc1_##J; \
        float c4 = (C4EXPR); \
        float h = ee * 1e38f; \
        float tc1 = -c3 * rr; \
        t0a = fmaxf(t0a, fminf(tc1, h)); \
        t1a = fminf(t1a, fmaxf(tc1, h)); \
        float tc2 = -c1 * rr; \
        t0b##J = fmaxf(t0b##J, fminf(tc2, -h)); \
        t1b##J = fminf(t1b##J, fmaxf(tc2, -h)); \
        mbmin##J = fminf(mbmin##J, c3); \
        rmax = fmaxf(rmax, c1); \
        float mn = fminf(fminf(fminf(c1, -c2), c3), -c4); \
        float mx = fmaxf(fmaxf(fmaxf(c1, -c2), c3), -c4); \
        float cx = rax*by##J - ray*bx##J; \
        hbp += (mn >= 0.f) ? cx : 0.f; \
        hbm += (mx <= 0.f) ? cx : 0.f; \
        pc1_##J = c1; pc3 = c3; }

    // Row for A-edge i (laundered A_i, r24-proven anti-hoist). Pair j=0
    // computes c4 directly (cycle seam); j=1..7 forward from pc3.
#define ROW(I,IN,IP) { \
        float rax = ax##I, ray = ay##I; \
        asm volatile("" : "+v"(rax), "+v"(ray) : "v"(hbp), "v"(hbm)); \
        const float reax = ax##IN - rax, reay = ay##IN - ray; \
        float t0a = 0.f, t1a = 1.f, rmax = -1e38f; \
        float pc3; \
        PAIR(0, (bx0 - rax)*eby7 - (by0 - ray)*ebx7) \
        PAIR(1, pc3) PAIR(2, pc3) PAIR(3, pc3) \
        PAIR(4, pc3) PAIR(5, pc3) PAIR(6, pc3) PAIR(7, pc3) \
        float cai = rax*ay##IN - ray*ax##IN; \
        areaA2 += cai; \
        float dt = t1a - t0a; \
        inter2 += fmaxf(dt, 0.f) * cai; \
        eSa += (rmax <= 0.f) ? cai : 0.f; }

    ROW(0,1,7) ROW(1,2,0) ROW(2,3,1) ROW(3,4,2)
    ROW(4,5,3) ROW(5,6,4) ROW(6,7,5) ROW(7,0,6)

    // B-edge tails: shoelace cb_j + clipped Green's term + hull mask term.
    float areaB2 = 0.f, eSb = 0.f;
#define BTAIL(J,JN) { \
        float cbj = bx##J*by##JN - by##J*bx##JN; \
        areaB2 += cbj; \
        float dt = t1b##J - t0b##J; \
        inter2 += fmaxf(dt, 0.f) * cbj; \
        eSb += (mbmin##J >= 0.f) ? cbj : 0.f; }
    BTAIL(0,1) BTAIL(1,2) BTAIL(2,3) BTAIL(3,4)
    BTAIL(4,5) BTAIL(5,6) BTAIL(6,7) BTAIL(7,0)

    float inter = fmaxf(0.5f * inter2, 0.f);
    float uni = 0.5f * areaA2 + 0.5f * areaB2 - inter;
    float iou = __fdividef(inter, uni);
    float ch = 0.5f * ((eSa + eSb) + (hbp - hbm));

    float val = iou - __fdividef(ch - uni, ch);
    float v = live ? val : 0.f;

    // ---- epilogue: shuffle -> LDS(16B) -> ONE plain store. Zero waits. ----
    #pragma unroll
    for (int off = 32; off > 0; off >>= 1) v += __shfl_down(v, off);
    __shared__ float wsum[4];
    int lane = t & 63, wid = t >> 6;
    if (lane == 0) wsum[wid] = v;
    __syncthreads();
    if (t == 0) {
        partial[blockIdx.x] = (double)wsum[0] + (double)wsum[1]
                            + (double)wsum[2] + (double)wsum[3];
    }
}

__global__ __launch_bounds__(256) void ciou_finalize(
    const double* __restrict__ partial, float* __restrict__ out,
    int nparts, int nbatch)
{
    double v = 0.0;
    for (int j = threadIdx.x; j < nparts; j += 256) v += partial[j];
    #pragma unroll
    for (int off = 32; off > 0; off >>= 1) v += __shfl_down(v, off);
    __shared__ double s[4];
    int lane = threadIdx.x & 63, wid = threadIdx.x >> 6;
    if (lane == 0) s[wid] = v;
    __syncthreads();
    if (threadIdx.x == 0)
        out[0] = (float)((s[0] + s[1] + s[2] + s[3]) / (double)nbatch);
}

extern "C" void kernel_launch(void* const* d_in, const int* in_sizes, int n_in,
                              void* d_out, int out_size, void* d_ws, size_t ws_size,
                              hipStream_t stream) {
    const float* a = (const float*)d_in[0];
    const float* b = (const float*)d_in[1];
    float* out = (float*)d_out;
    int nbatch = in_sizes[0] / 16;
    int nblocks = (nbatch + TPB - 1) / TPB;   // 262144 -> 1024, exact
    int tail = (nblocks * TPB != nbatch) ? 1 : 0;
    double* partial = (double*)d_ws;   // fully overwritten each call; no memset
    ciou_main<<<nblocks, TPB, 0, stream>>>(a, b, partial, nbatch, tail);
    ciou_finalize<<<1, 256, 0, stream>>>(partial, out, nblocks, nbatch);
}